// Round 7
// baseline (437.215 us; speedup 1.0000x reference)
//
#include <hip/hip_runtime.h>

#define N_ROWS 8192
#define DIM    512

typedef __attribute__((ext_vector_type(4))) float frag_cd;      // 4 fp32 acc
typedef __attribute__((ext_vector_type(2))) long long v2ll;     // 16B = 2 fp8 fragments

// fp32 -> OCP e4m3fn, RNE, FTZ below 2^-6 (negligible for N(0,1) data).
__device__ __forceinline__ unsigned f2fp8(float x) {
    float a = fabsf(x);
    unsigned s = (__float_as_uint(x) >> 31) << 7;
    if (a < 0.015625f) return s;                 // FTZ subnormals
    a = fminf(a, 448.f);                         // e4m3fn max
    unsigned u = __float_as_uint(a);
    u += 0x7FFFFu + ((u >> 20) & 1u);            // RNE round mantissa to 3 bits
    unsigned exp = (u >> 23) - 120u;             // fp32exp-127+7 in [1,15]
    unsigned mant = (u >> 20) & 7u;
    return s | (exp << 3) | mant;
}
__device__ __forceinline__ unsigned pack4fp8(float4 v) {
    return f2fp8(v.x) | (f2fp8(v.y) << 8) | (f2fp8(v.z) << 16) | (f2fp8(v.w) << 24);
}
// order-preserving f32 -> u32 key (monotone), so atomicMax(uint) == float max
__device__ __forceinline__ unsigned enc_f32(float f) {
    unsigned u = __float_as_uint(f);
    return (u & 0x80000000u) ? ~u : (u | 0x80000000u);
}
__device__ __forceinline__ float dec_f32(unsigned k) {
    return __uint_as_float((k & 0x80000000u) ? (k & 0x7FFFFFFFu) : ~k);
}

// ---- TILED fp8 layout (rounds 0-6 verified exact) ----
// Pair-chunk (cr, kp) = 16 rows x 64 K-cols = 1 KB, 64 units of 16B.
// Byte addr = cr*8192 + kp*1024 + u*16. Consumer lane reads 16B at lane*16:
// contiguous across the wave -> 0 LDS bank conflicts (measured rounds 1-6).

// ---- kernel 1: convert + diag + init (round-0/1 verbatim, verified) ----
__global__ __launch_bounds__(256) void k_prep(const float* __restrict__ imgs,
                                              const float* __restrict__ caps,
                                              unsigned char* __restrict__ fimgs,
                                              unsigned char* __restrict__ fcaps,
                                              float* __restrict__ diag,
                                              unsigned* __restrict__ rowmax,
                                              unsigned* __restrict__ colmax,
                                              float* __restrict__ out) {
    const int cr = blockIdx.x;            // 0..511
    const int t  = threadIdx.x;
    const int w = t >> 6, l = t & 63;
    const int kp = l >> 3, cg = l & 3, par = (l >> 2) & 1;
    if (cr == 0 && t == 0) out[0] = 0.f;  // zero accumulator for k_final's atomics
    const size_t ubase = (size_t)cr * 8192 + kp * 1024 + cg * 256 + par * 8;
    float ps[4];
    #pragma unroll
    for (int i = 0; i < 4; ++i) {
        const int row = w + 4 * i;                 // 0..15
        const float* ar = imgs + ((size_t)cr * 16 + row) * DIM + l * 8;
        const float* br = caps + ((size_t)cr * 16 + row) * DIM + l * 8;
        float4 a0 = *(const float4*)ar, a1 = *(const float4*)(ar + 4);
        float4 b0 = *(const float4*)br, b1 = *(const float4*)(br + 4);
        uint2 oa, ob;
        oa.x = pack4fp8(a0); oa.y = pack4fp8(a1);
        ob.x = pack4fp8(b0); ob.y = pack4fp8(b1);
        *(uint2*)(fimgs + ubase + row * 16) = oa;
        *(uint2*)(fcaps + ubase + row * 16) = ob;
        ps[i] = a0.x * b0.x + a0.y * b0.y + a0.z * b0.z + a0.w * b0.w
              + a1.x * b1.x + a1.y * b1.y + a1.z * b1.z + a1.w * b1.w;
    }
    #pragma unroll
    for (int i = 0; i < 4; ++i) {
        float s = ps[i];
        #pragma unroll
        for (int m = 1; m < 64; m <<= 1) s += __shfl_xor(s, m, 64);
        if (l == 0) {
            const int r = cr * 16 + w + 4 * i;
            diag[r] = s; rowmax[r] = 0u; colmax[r] = 0u;
        }
    }
}

// ---- kernel 2: fp8 NT-GEMM -- 256x128 block, 8 waves, cheap-wait dbuf ----
// Round-6 post-mortem: 93 us invariant across schedules at 128x128 ->
// per-iteration latency exposed, too little MFMA per CU per iteration.
// This version: block 256x128, 8 waves (512 thr) as 4M x 2N, each 64x64
// (acc[4][4] -- round-6-verified epilogue). Per block-iter: 8x32 MFMA
// (~1240 cy/CU) vs LDS-port ~600 cy and 24 KB staging -> MFMA-bound.
// 2 buffers x 24 KB = 48 KB -> 3 blocks/CU (24 waves, 3 streams).
// Cheap-wait: entry vmcnt(0) waits only on loads issued a FULL iteration
// ago (~free), and runs BEFORE stage(t+1) issue, so prefetch is never
// drained (unlike round-1's __syncthreads). Overwrite safety: stage(t+1)
// targets buf[(t-1)&1]; its readers' ds_reads completed before this
// iter's entry wait (lgkmcnt(0)) + barrier.
__global__ __launch_bounds__(512, 6) void k_gemm(const unsigned char* __restrict__ A,
                                                 const unsigned char* __restrict__ B,
                                                 unsigned* __restrict__ rowmax,
                                                 unsigned* __restrict__ colmax) {
    __shared__ unsigned char sA[2][16384];   // 2 bufs x 16 chunks x 1 KB (256 rows)
    __shared__ unsigned char sB[2][8192];    // 2 bufs x  8 chunks x 1 KB (128 cols)
    const int tid = threadIdx.x;
    const int w = tid >> 6, lane = tid & 63;
    // XCD-aware bijective swizzle (grid 2048 = 64jb x 32ib, 2048%8==0).
    // xcd f&7 owns 8 jb-panels (512 KB of B, L2-resident).
    const int f = (int)blockIdx.x;
    const int jb = (f & 7) * 8 + ((f >> 3) & 7);   // 0..63 (128-col panel)
    const int ib = f >> 6;                          // 0..31 (256-row panel)
    const int j0 = jb << 7, i0 = ib << 8;
    const int q = lane >> 4, l15 = lane & 15;
    const int wm = w >> 1, wn = w & 1;
    const int wr = wm << 6, wc = wn << 6;           // wave tile origin (64x64)

    const unsigned char* Ab = A + (size_t)(i0 >> 4) * 8192 + lane * 16;
    const unsigned char* Bb = B + (size_t)(j0 >> 4) * 8192 + lane * 16;

    // wave w stages A chunks {2w,2w+1} (rows w*32..+31) and B chunk w
    auto stage = [&](int t) {
        const int buf = t & 1;
        #pragma unroll
        for (int j = 0; j < 2; ++j) {
            const int ch = 2 * w + j;
            __builtin_amdgcn_global_load_lds(
                (const __attribute__((address_space(1))) unsigned int*)(Ab + (size_t)ch * 8192 + t * 1024),
                (__attribute__((address_space(3))) unsigned int*)(&sA[buf][(ch << 10) + (lane << 4)]), 16, 0, 0);
        }
        __builtin_amdgcn_global_load_lds(
            (const __attribute__((address_space(1))) unsigned int*)(Bb + (size_t)w * 8192 + t * 1024),
            (__attribute__((address_space(3))) unsigned int*)(&sB[buf][(w << 10) + (lane << 4)]), 16, 0, 0);
    };

    stage(0);
    asm volatile("s_waitcnt vmcnt(0)" ::: "memory");
    __builtin_amdgcn_s_barrier();

    frag_cd acc[4][4] = {};
    const int ca0 = wm << 2, cb0 = wn << 2;   // fragment chunk bases
    const int u16 = lane << 4;

    #pragma unroll
    for (int t = 0; t < 8; ++t) {
        if (t > 0) {
            // all tile-t loads (issued one full iteration ago) done;
            // my ds_reads of iter t-1 done -> barrier makes both global.
            asm volatile("s_waitcnt vmcnt(0) lgkmcnt(0)" ::: "memory");
            __builtin_amdgcn_s_barrier();
        }
        if (t < 7) stage(t + 1);   // full iteration of slack to complete

        v2ll af[4], bf[4];
        #pragma unroll
        for (int m = 0; m < 4; ++m)
            af[m] = *(const v2ll*)(&sA[t & 1][((ca0 + m) << 10) + u16]);
        #pragma unroll
        for (int n = 0; n < 4; ++n)
            bf[n] = *(const v2ll*)(&sB[t & 1][((cb0 + n) << 10) + u16]);

        __builtin_amdgcn_s_setprio(1);
        #pragma unroll
        for (int m = 0; m < 4; ++m)
            #pragma unroll
            for (int n = 0; n < 4; ++n)
                acc[m][n] = __builtin_amdgcn_mfma_f32_16x16x32_fp8_fp8(af[m][0], bf[n][0], acc[m][n], 0, 0, 0);
        #pragma unroll
        for (int m = 0; m < 4; ++m)
            #pragma unroll
            for (int n = 0; n < 4; ++n)
                acc[m][n] = __builtin_amdgcn_mfma_f32_16x16x32_fp8_fp8(af[m][1], bf[n][1], acc[m][n], 0, 0, 0);
        __builtin_amdgcn_s_setprio(0);
    }

    // ---- epilogue: diagonal flip + row/col max (rounds 3-6 verified) ----
    // C/D layout (16x16 family): col = lane&15, row = (lane>>4)*4 + reg
    const bool dblk = ((j0 >> 8) == ib);   // 128-col panel inside 256-row panel
    #pragma unroll
    for (int r = 0; r < 4; ++r)
        #pragma unroll
        for (int c = 0; c < 4; ++c)
            #pragma unroll
            for (int g = 0; g < 4; ++g) {
                float fv = acc[r][c][g];
                const int gi = wr + (r << 4) + (q << 2) + g;          // row in block
                const int gj = wc + (c << 4) + l15;                   // col in block
                if (dblk && (i0 + gi) == (j0 + gj)) fv = -fv;         // s[i][i] = -diag
                acc[r][c][g] = fv;
            }

    #pragma unroll
    for (int r = 0; r < 4; ++r)
        #pragma unroll
        for (int g = 0; g < 4; ++g) {
            float m = fmaxf(fmaxf(acc[r][0][g], acc[r][1][g]),
                            fmaxf(acc[r][2][g], acc[r][3][g]));
            m = fmaxf(m, __shfl_xor(m, 1, 64));
            m = fmaxf(m, __shfl_xor(m, 2, 64));
            m = fmaxf(m, __shfl_xor(m, 4, 64));
            m = fmaxf(m, __shfl_xor(m, 8, 64));
            if (l15 == 0)
                atomicMax(&rowmax[i0 + wr + (r << 4) + (q << 2) + g], enc_f32(m));
        }
    #pragma unroll
    for (int c = 0; c < 4; ++c) {
        float m = acc[0][c][0];
        #pragma unroll
        for (int r = 0; r < 4; ++r)
            #pragma unroll
            for (int g = 0; g < 4; ++g) m = fmaxf(m, acc[r][c][g]);
        m = fmaxf(m, __shfl_xor(m, 16, 64));
        m = fmaxf(m, __shfl_xor(m, 32, 64));
        if (q == 0)
            atomicMax(&colmax[j0 + wc + (c << 4) + l15], enc_f32(m));
    }
}

// ---- kernel 3: hinge terms, 32 blocks + one atomicAdd per block ----
__global__ __launch_bounds__(256) void k_final(const unsigned* __restrict__ rowmax,
                                               const unsigned* __restrict__ colmax,
                                               const float* __restrict__ diag,
                                               float* __restrict__ out) {
    const int idx = blockIdx.x * 256 + threadIdx.x;
    const float d = diag[idx];
    float s = fmaxf(dec_f32(rowmax[idx]) + 0.2f - d, 0.f)    // neg_img
            + fmaxf(dec_f32(colmax[idx]) + 0.2f - d, 0.f);   // neg_cap
    #pragma unroll
    for (int m = 1; m < 64; m <<= 1) s += __shfl_xor(s, m, 64);
    __shared__ float red[4];
    if ((threadIdx.x & 63) == 0) red[threadIdx.x >> 6] = s;
    __syncthreads();
    if (threadIdx.x == 0)
        atomicAdd(out, red[0] + red[1] + red[2] + red[3]);
}

extern "C" void kernel_launch(void* const* d_in, const int* in_sizes, int n_in,
                              void* d_out, int out_size, void* d_ws, size_t ws_size,
                              hipStream_t stream) {
    const float* imgs = (const float*)d_in[0];
    const float* caps = (const float*)d_in[1];
    float* out = (float*)d_out;

    char* ws = (char*)d_ws;
    unsigned char* fimgs = (unsigned char*)ws;                         // 4 MB tiled fp8
    unsigned char* fcaps = (unsigned char*)(ws + 4194304);             // 4 MB tiled fp8
    float*    diag   = (float*)   (ws + 8388608);                      // 32 KB
    unsigned* rowmax = (unsigned*)(ws + 8388608 + 32768);              // 32 KB
    unsigned* colmax = (unsigned*)(ws + 8388608 + 65536);              // 32 KB

    k_prep<<<N_ROWS / 16, 256, 0, stream>>>(imgs, caps, fimgs, fcaps,
                                            diag, rowmax, colmax, out);
    k_gemm<<<2048, 512, 0, stream>>>(fimgs, fcaps, rowmax, colmax);
    k_final<<<N_ROWS / 256, 256, 0, stream>>>(rowmax, colmax, diag, out);
}

// Round 8
// 193.063 us; speedup vs baseline: 2.2646x; 2.2646x over previous
//
#include <hip/hip_runtime.h>

#define N_ROWS 8192
#define DIM    512

typedef __attribute__((ext_vector_type(4))) float frag_cd;      // 4 fp32 acc
typedef __attribute__((ext_vector_type(2))) long long v2ll;     // 16B = 2 fp8 fragments

// fp32 -> OCP e4m3fn, RNE, FTZ below 2^-6 (negligible for N(0,1) data).
__device__ __forceinline__ unsigned f2fp8(float x) {
    float a = fabsf(x);
    unsigned s = (__float_as_uint(x) >> 31) << 7;
    if (a < 0.015625f) return s;                 // FTZ subnormals
    a = fminf(a, 448.f);                         // e4m3fn max
    unsigned u = __float_as_uint(a);
    u += 0x7FFFFu + ((u >> 20) & 1u);            // RNE round mantissa to 3 bits
    unsigned exp = (u >> 23) - 120u;             // fp32exp-127+7 in [1,15]
    unsigned mant = (u >> 20) & 7u;
    return s | (exp << 3) | mant;
}
__device__ __forceinline__ unsigned pack4fp8(float4 v) {
    return f2fp8(v.x) | (f2fp8(v.y) << 8) | (f2fp8(v.z) << 16) | (f2fp8(v.w) << 24);
}
// order-preserving f32 -> u32 key (monotone), so atomicMax(uint) == float max
__device__ __forceinline__ unsigned enc_f32(float f) {
    unsigned u = __float_as_uint(f);
    return (u & 0x80000000u) ? ~u : (u | 0x80000000u);
}
__device__ __forceinline__ float dec_f32(unsigned k) {
    return __uint_as_float((k & 0x80000000u) ? (k & 0x7FFFFFFFu) : ~k);
}

// ---- TILED fp8 layout (rounds 0-6 verified exact) ----
// Pair-chunk (cr, kp) = 16 rows x 64 K-cols = 1 KB, 64 units of 16B.
// Byte addr = cr*8192 + kp*1024 + u*16. Consumer lane reads 16B at lane*16:
// contiguous across the wave -> 0 LDS bank conflicts (measured rounds 1-6).

// ---- kernel 1: convert + diag + init (round-0/1 verbatim, verified) ----
__global__ __launch_bounds__(256) void k_prep(const float* __restrict__ imgs,
                                              const float* __restrict__ caps,
                                              unsigned char* __restrict__ fimgs,
                                              unsigned char* __restrict__ fcaps,
                                              float* __restrict__ diag,
                                              unsigned* __restrict__ rowmax,
                                              unsigned* __restrict__ colmax,
                                              float* __restrict__ out) {
    const int cr = blockIdx.x;            // 0..511
    const int t  = threadIdx.x;
    const int w = t >> 6, l = t & 63;
    const int kp = l >> 3, cg = l & 3, par = (l >> 2) & 1;
    if (cr == 0 && t == 0) out[0] = 0.f;  // zero accumulator for k_final's atomics
    const size_t ubase = (size_t)cr * 8192 + kp * 1024 + cg * 256 + par * 8;
    float ps[4];
    #pragma unroll
    for (int i = 0; i < 4; ++i) {
        const int row = w + 4 * i;                 // 0..15
        const float* ar = imgs + ((size_t)cr * 16 + row) * DIM + l * 8;
        const float* br = caps + ((size_t)cr * 16 + row) * DIM + l * 8;
        float4 a0 = *(const float4*)ar, a1 = *(const float4*)(ar + 4);
        float4 b0 = *(const float4*)br, b1 = *(const float4*)(br + 4);
        uint2 oa, ob;
        oa.x = pack4fp8(a0); oa.y = pack4fp8(a1);
        ob.x = pack4fp8(b0); ob.y = pack4fp8(b1);
        *(uint2*)(fimgs + ubase + row * 16) = oa;
        *(uint2*)(fcaps + ubase + row * 16) = ob;
        ps[i] = a0.x * b0.x + a0.y * b0.y + a0.z * b0.z + a0.w * b0.w
              + a1.x * b1.x + a1.y * b1.y + a1.z * b1.z + a1.w * b1.w;
    }
    #pragma unroll
    for (int i = 0; i < 4; ++i) {
        float s = ps[i];
        #pragma unroll
        for (int m = 1; m < 64; m <<= 1) s += __shfl_xor(s, m, 64);
        if (l == 0) {
            const int r = cr * 16 + w + 4 * i;
            diag[r] = s; rowmax[r] = 0u; colmax[r] = 0u;
        }
    }
}

// ---- kernel 2: fp8 NT-GEMM -- 256x256 8-phase template (m201 port) ----
// 8 waves (2M x 4N), wave tile 128x64 (acc[8][4]), BK=64, 4 K-tile LDS
// slots (128 KB), grid 1024. Per phase: 6 ds_read_b128 (one C-quadrant's
// frags) || 1 global_load_lds unit -> barrier -> lgkmcnt(0)+sched_barrier
// -> setprio(1) + 16 MFMA + setprio(0) -> trailing barrier. Counted vmcnt
// ONLY at phases 3/7: ledger (prologue 12 loads, 4/K-tile, units complete
// in issue order): it0p3 need KT1: issued16 -> vmcnt(8); it0p7 need KT2:
// issued20 -> 8; it1p3/p7, it2p3 -> 8; it2p7 need KT6: issued32 -> 4;
// it3p3 need KT7 -> 0. Ring safety: stage(KT t+3 -> slot (t+3)&3) and
// stage(KT t+4 -> slot t&3) both target slots whose readers' ds_reads
// completed before an earlier lgkmcnt(0)+barrier in this iter.
__global__ __launch_bounds__(512, 2) void k_gemm(const unsigned char* __restrict__ A,
                                                 const unsigned char* __restrict__ B,
                                                 unsigned* __restrict__ rowmax,
                                                 unsigned* __restrict__ colmax) {
    __shared__ unsigned char sA[4][16384];   // 4 K-tile slots x 16 chunks x 1 KB
    __shared__ unsigned char sB[4][16384];
    const int tid = threadIdx.x;
    const int w = tid >> 6, lane = tid & 63;   // 8 waves
    // XCD-aware bijective swizzle (grid 1024 = 32jb x 32ib, 1024%8==0).
    // xcd f&7 owns 4 jb-panels (512 KB of B, L2-resident).
    const int f = (int)blockIdx.x;
    const int jb = (f & 7) * 4 + ((f >> 3) & 3);   // 0..31
    const int ib = f >> 5;                          // 0..31
    const int j0 = jb << 8, i0 = ib << 8;
    const int q = lane >> 4, l15 = lane & 15;
    const int wm = w >> 2, wn = w & 3;
    const int wr = wm << 7, wc = wn << 6;           // wave tile origin 128x64

    const unsigned char* Abase = A + (size_t)(i0 >> 4) * 8192;
    const unsigned char* Bbase = B + (size_t)(j0 >> 4) * 8192;

    // unit u of K-tile t: u0 = A chunks 0-7, u1 = A 8-15, u2 = B 0-7, u3 = B 8-15
    // (8 KB = 512 threads x 16 B each; chunk = w + 8*(u&1))
    auto stage_unit = [&](int t, int u) {
        const int ch = ((u & 1) << 3) + w;
        const unsigned char* gsrc = ((u < 2) ? Abase : Bbase)
                                  + (size_t)ch * 8192 + t * 1024 + (lane << 4);
        unsigned char* ldst = ((u < 2) ? &sA[t & 3][0] : &sB[t & 3][0])
                            + (ch << 10) + (lane << 4);
        __builtin_amdgcn_global_load_lds(
            (const __attribute__((address_space(1))) unsigned int*)gsrc,
            (__attribute__((address_space(3))) unsigned int*)ldst, 16, 0, 0);
    };

    // prologue: stage KT0,1,2 (12 loads/thread); wait KT0 (8 newest in flight)
    #pragma unroll
    for (int t = 0; t < 3; ++t)
        #pragma unroll
        for (int u = 0; u < 4; ++u) stage_unit(t, u);
    asm volatile("s_waitcnt vmcnt(8)" ::: "memory");
    __builtin_amdgcn_s_barrier();

    frag_cd acc[8][4] = {};   // 128 VGPR accumulator

    #pragma unroll
    for (int it = 0; it < 4; ++it) {
        #pragma unroll
        for (int p = 0; p < 8; ++p) {
            const int kt = 2 * it + (p >> 2);          // current K-tile
            const int qq = p & 3, qr = qq >> 1, qc = qq & 1;   // C-quadrant

            // ds-load this quadrant's fragments (all compile-time indices)
            v2ll av[4], bv[2];
            #pragma unroll
            for (int rr = 0; rr < 4; ++rr)
                av[rr] = *(const v2ll*)(&sA[kt & 3][((((wm << 3) + (qr << 2) + rr)) << 10) + (lane << 4)]);
            #pragma unroll
            for (int cc = 0; cc < 2; ++cc)
                bv[cc] = *(const v2ll*)(&sB[kt & 3][((((wn << 2) + (qc << 1) + cc)) << 10) + (lane << 4)]);

            // stage one 8KB unit of a future K-tile (1 gload_lds/thread/phase)
            const int ts = 2 * it + 3 + (p >> 2);
            if (ts < 8) stage_unit(ts, p & 3);

            __builtin_amdgcn_s_barrier();
            asm volatile("s_waitcnt lgkmcnt(0)" ::: "memory");
            __builtin_amdgcn_sched_barrier(0);   // rule #18: pin MFMA after wait

            __builtin_amdgcn_s_setprio(1);
            #pragma unroll
            for (int rr = 0; rr < 4; ++rr)
                #pragma unroll
                for (int cc = 0; cc < 2; ++cc)
                    acc[(qr << 2) + rr][(qc << 1) + cc] =
                        __builtin_amdgcn_mfma_f32_16x16x32_fp8_fp8(
                            av[rr][0], bv[cc][0], acc[(qr << 2) + rr][(qc << 1) + cc], 0, 0, 0);
            #pragma unroll
            for (int rr = 0; rr < 4; ++rr)
                #pragma unroll
                for (int cc = 0; cc < 2; ++cc)
                    acc[(qr << 2) + rr][(qc << 1) + cc] =
                        __builtin_amdgcn_mfma_f32_16x16x32_fp8_fp8(
                            av[rr][1], bv[cc][1], acc[(qr << 2) + rr][(qc << 1) + cc], 0, 0, 0);
            __builtin_amdgcn_s_setprio(0);

            // trailing barrier; counted vmcnt once per K-tile (phases 3, 7)
            if (p == 3) {
                if (it == 3) asm volatile("s_waitcnt vmcnt(0)" ::: "memory");
                else         asm volatile("s_waitcnt vmcnt(8)" ::: "memory");
            } else if (p == 7 && it < 3) {
                if (it == 2) asm volatile("s_waitcnt vmcnt(4)" ::: "memory");
                else         asm volatile("s_waitcnt vmcnt(8)" ::: "memory");
            }
            __builtin_amdgcn_s_barrier();
        }
    }

    // ---- epilogue: diagonal flip + row/col max (rounds 3-6 verified) ----
    // C/D layout (16x16 family): col = lane&15, row = (lane>>4)*4 + reg
    const bool dblk = (i0 == j0);
    #pragma unroll
    for (int r = 0; r < 8; ++r)
        #pragma unroll
        for (int c = 0; c < 4; ++c)
            #pragma unroll
            for (int g = 0; g < 4; ++g) {
                float fv = acc[r][c][g];
                const int gi = wr + (r << 4) + (q << 2) + g;          // row in block
                const int gj = wc + (c << 4) + l15;                   // col in block
                if (dblk && gi == gj) fv = -fv;                       // s[i][i] = -diag
                acc[r][c][g] = fv;
            }

    #pragma unroll
    for (int r = 0; r < 8; ++r)
        #pragma unroll
        for (int g = 0; g < 4; ++g) {
            float m = fmaxf(fmaxf(acc[r][0][g], acc[r][1][g]),
                            fmaxf(acc[r][2][g], acc[r][3][g]));
            m = fmaxf(m, __shfl_xor(m, 1, 64));
            m = fmaxf(m, __shfl_xor(m, 2, 64));
            m = fmaxf(m, __shfl_xor(m, 4, 64));
            m = fmaxf(m, __shfl_xor(m, 8, 64));
            if (l15 == 0)
                atomicMax(&rowmax[i0 + wr + (r << 4) + (q << 2) + g], enc_f32(m));
        }
    #pragma unroll
    for (int c = 0; c < 4; ++c) {
        float m = acc[0][c][0];
        #pragma unroll
        for (int r = 0; r < 8; ++r)
            #pragma unroll
            for (int g = 0; g < 4; ++g) m = fmaxf(m, acc[r][c][g]);
        m = fmaxf(m, __shfl_xor(m, 16, 64));
        m = fmaxf(m, __shfl_xor(m, 32, 64));
        if (q == 0)
            atomicMax(&colmax[j0 + wc + (c << 4) + l15], enc_f32(m));
    }
}

// ---- kernel 3: hinge terms, 32 blocks + one atomicAdd per block ----
__global__ __launch_bounds__(256) void k_final(const unsigned* __restrict__ rowmax,
                                               const unsigned* __restrict__ colmax,
                                               const float* __restrict__ diag,
                                               float* __restrict__ out) {
    const int idx = blockIdx.x * 256 + threadIdx.x;
    const float d = diag[idx];
    float s = fmaxf(dec_f32(rowmax[idx]) + 0.2f - d, 0.f)    // neg_img
            + fmaxf(dec_f32(colmax[idx]) + 0.2f - d, 0.f);   // neg_cap
    #pragma unroll
    for (int m = 1; m < 64; m <<= 1) s += __shfl_xor(s, m, 64);
    __shared__ float red[4];
    if ((threadIdx.x & 63) == 0) red[threadIdx.x >> 6] = s;
    __syncthreads();
    if (threadIdx.x == 0)
        atomicAdd(out, red[0] + red[1] + red[2] + red[3]);
}

extern "C" void kernel_launch(void* const* d_in, const int* in_sizes, int n_in,
                              void* d_out, int out_size, void* d_ws, size_t ws_size,
                              hipStream_t stream) {
    const float* imgs = (const float*)d_in[0];
    const float* caps = (const float*)d_in[1];
    float* out = (float*)d_out;

    char* ws = (char*)d_ws;
    unsigned char* fimgs = (unsigned char*)ws;                         // 4 MB tiled fp8
    unsigned char* fcaps = (unsigned char*)(ws + 4194304);             // 4 MB tiled fp8
    float*    diag   = (float*)   (ws + 8388608);                      // 32 KB
    unsigned* rowmax = (unsigned*)(ws + 8388608 + 32768);              // 32 KB
    unsigned* colmax = (unsigned*)(ws + 8388608 + 65536);              // 32 KB

    k_prep<<<N_ROWS / 16, 256, 0, stream>>>(imgs, caps, fimgs, fcaps,
                                            diag, rowmax, colmax, out);
    k_gemm<<<1024, 512, 0, stream>>>(fimgs, fcaps, rowmax, colmax);
    k_final<<<N_ROWS / 256, 256, 0, stream>>>(rowmax, colmax, diag, out);
}